// Round 6
// baseline (488.583 us; speedup 1.0000x reference)
//
#include <hip/hip_runtime.h>

#define NS 500000
#define NG 20000
#define NN 600000
#define NF 8
#define EPS_ 1e-5f

// ---------------- K1: w = mean_f filters; also copy filters -> out ----------------
__global__ __launch_bounds__(256) void k_w_copy(const float* __restrict__ filters,
                                                float* __restrict__ w,
                                                float* __restrict__ out_f) {
  int i = blockIdx.x * 256 + threadIdx.x;
  const int n4 = NS / 4;  // 125000
  if (i >= n4) return;
  const float4* f4 = (const float4*)filters;
  float4* o4 = (float4*)out_f;
  float sx = 0.f, sy = 0.f, sz = 0.f, sw = 0.f;
#pragma unroll
  for (int f = 0; f < NF; f++) {
    float4 v = f4[(size_t)f * n4 + i];
    o4[(size_t)f * n4 + i] = v;
    sx += v.x; sy += v.y; sz += v.z; sw += v.w;
  }
  float4 r;
  r.x = sx * 0.125f; r.y = sy * 0.125f; r.z = sz * 0.125f; r.w = sw * 0.125f;
  ((float4*)w)[i] = r;
}

// ---------------- hist + mark used sids (merged, one pass) ----------------
__global__ __launch_bounds__(256) void k_hist_mark(const int* __restrict__ snp_ids,
                                                   const int* __restrict__ node_gene,
                                                   int* __restrict__ cnt,
                                                   unsigned char* __restrict__ used) {
  int j = blockIdx.x * 256 + threadIdx.x;
  if (j < NN) {
    used[snp_ids[j]] = 1;
    atomicAdd(&cnt[node_gene[j]], 1);
  }
}

__global__ __launch_bounds__(1024) void k_scan(const int* __restrict__ cnt,
                                               int* __restrict__ offs,
                                               int* __restrict__ cursor) {
  __shared__ int part[1024];
  int t = threadIdx.x;
  int base = t * 20;  // 1024*20 = 20480 >= 20000
  int s = 0;
  for (int i = 0; i < 20; i++) {
    int g = base + i;
    if (g < NG) s += cnt[g];
  }
  part[t] = s;
  __syncthreads();
  for (int d = 1; d < 1024; d <<= 1) {
    int v = 0;
    if (t >= d) v = part[t - d];
    __syncthreads();
    part[t] += v;
    __syncthreads();
  }
  int run = part[t] - s;
  for (int i = 0; i < 20; i++) {
    int g = base + i;
    if (g < NG) {
      offs[g] = run;
      cursor[g] = run;
      run += cnt[g];
    }
  }
  if (t == 1023) offs[NG] = part[1023];
}

__global__ __launch_bounds__(256) void k_sortnodes(const int* __restrict__ snp_ids,
                                                   const int* __restrict__ node_gene,
                                                   int* __restrict__ cursor,
                                                   int* __restrict__ sorted_sid) {
  int j = blockIdx.x * 256 + threadIdx.x;
  if (j >= NN) return;
  int g = node_gene[j];
  int pos = atomicAdd(&cursor[g], 1);
  sorted_sid[pos] = snp_ids[j];
}

// ---------------- transpose v5: pipelined multi-tile, double-buffered LDS ----------
// Each block processes 4 consecutive 64-sid tiles. While tile t's store phase
// drains buf[t&1], tile t+1's global loads (issued before the store phase) are in
// flight; its ds_write lands in buf[t&1^1] after. One barrier per tile.
__global__ __launch_bounds__(256) void k_transpose(const float* __restrict__ snp,
                                                   const float* __restrict__ w,
                                                   const unsigned char* __restrict__ used,
                                                   float* __restrict__ snpT) {
  __shared__ float tile[2][64 * 64];  // swizzled float4 chunks: chunk(b,f)=b*16+(f^(b&15))
  const int NT = (NS + 63) / 64;      // 7813
  int t = threadIdx.x;
  int f = t & 15;
  int r = (t >> 4) & 3;
  int wq = t >> 6;
  int b = t & 63;
  int sq = t >> 6;

  int t0 = blockIdx.x * 4;
  if (t0 >= NT) return;

  float4 cw;
  float4 cv[4];
  unsigned cu32[4];

  // ---- prologue: load + stage tile t0, prefetch its used bits ----
  {
    int s0 = t0 * 64;
    bool okf = (s0 + 4 * f + 4 <= NS);
    cw = make_float4(0.f, 0.f, 0.f, 0.f);
    if (okf) cw = *(const float4*)(w + s0 + 4 * f);
#pragma unroll
    for (int i = 0; i < 4; i++) {
      int bb = wq * 16 + i * 4 + r;
      cv[i] = make_float4(0.f, 0.f, 0.f, 0.f);
      if (okf) cv[i] = *(const float4*)(snp + (size_t)bb * NS + s0 + 4 * f);
    }
    int ubase = s0 + sq * 16;
    if (ubase + 16 <= NS) {
      uint4 ub = *(const uint4*)(used + ubase);
      cu32[0] = ub.x; cu32[1] = ub.y; cu32[2] = ub.z; cu32[3] = ub.w;
    } else {
#pragma unroll
      for (int i = 0; i < 4; i++) {
        unsigned vv = 0;
#pragma unroll
        for (int kk = 0; kk < 4; kk++) {
          int s = ubase + 4 * i + kk;
          if (s < NS && used[s]) vv |= (1u << (8 * kk));
        }
        cu32[i] = vv;
      }
    }
#pragma unroll
    for (int i = 0; i < 4; i++) {
      int bb = wq * 16 + i * 4 + r;
      float4 x = cv[i];
      x.x *= cw.x; x.y *= cw.y; x.z *= cw.z; x.w *= cw.w;
      ((float4*)tile[0])[bb * 16 + (f ^ (bb & 15))] = x;
    }
  }
  __syncthreads();

  for (int k = 0; k < 4; k++) {
    int tt = t0 + k;
    if (tt >= NT) break;
    int cur = k & 1;
    bool hasNext = (k + 1 < 4) && (tt + 1 < NT);

    // ---- issue next tile's global loads early (overlap with store phase) ----
    float4 nw = make_float4(0.f, 0.f, 0.f, 0.f);
    float4 nv[4];
    unsigned nu32[4];
    if (hasNext) {
      int s0 = (tt + 1) * 64;
      bool okf = (s0 + 4 * f + 4 <= NS);
      if (okf) nw = *(const float4*)(w + s0 + 4 * f);
#pragma unroll
      for (int i = 0; i < 4; i++) {
        int bb = wq * 16 + i * 4 + r;
        nv[i] = make_float4(0.f, 0.f, 0.f, 0.f);
        if (okf) nv[i] = *(const float4*)(snp + (size_t)bb * NS + s0 + 4 * f);
      }
      int ubase = s0 + sq * 16;
      if (ubase + 16 <= NS) {
        uint4 ub = *(const uint4*)(used + ubase);
        nu32[0] = ub.x; nu32[1] = ub.y; nu32[2] = ub.z; nu32[3] = ub.w;
      } else {
#pragma unroll
        for (int i = 0; i < 4; i++) {
          unsigned vv = 0;
#pragma unroll
          for (int kk = 0; kk < 4; kk++) {
            int s = ubase + 4 * i + kk;
            if (s < NS && used[s]) vv |= (1u << (8 * kk));
          }
          nu32[i] = vv;
        }
      }
    }

    // ---- store phase for tile tt from tile[cur] ----
    int s0c = tt * 64;
#pragma unroll
    for (int i = 0; i < 4; i++) {
      int s4 = sq * 4 + i;
      float4 x = ((const float4*)tile[cur])[b * 16 + (s4 ^ (b & 15))];
      int sb = s0c + 4 * s4;
      float xv[4] = {x.x, x.y, x.z, x.w};
#pragma unroll
      for (int kk = 0; kk < 4; kk++) {
        int s = sb + kk;
        bool u = ((cu32[i] >> (8 * kk)) & 0xFFu) != 0;  // wave-uniform
        if (s < NS && u) snpT[(size_t)s * 64 + b] = xv[kk];
      }
    }

    // ---- stage next tile into the other buffer ----
    if (hasNext) {
#pragma unroll
      for (int i = 0; i < 4; i++) {
        int bb = wq * 16 + i * 4 + r;
        float4 x = nv[i];
        x.x *= nw.x; x.y *= nw.y; x.z *= nw.z; x.w *= nw.w;
        ((float4*)tile[cur ^ 1])[bb * 16 + (f ^ (bb & 15))] = x;
      }
      cu32[0] = nu32[0]; cu32[1] = nu32[1]; cu32[2] = nu32[2]; cu32[3] = nu32[3];
    }
    __syncthreads();
  }
}

// ---------------- accum v3: wave per gene, lane = batch, 8-node ILP ----------------
__global__ __launch_bounds__(256) void k_accum_T(const float* __restrict__ snpT,
                                                 const int* __restrict__ offs,
                                                 const int* __restrict__ sorted_sid,
                                                 float* __restrict__ geneT) {
  int wave = (blockIdx.x * 256 + threadIdx.x) >> 6;
  int lane = threadIdx.x & 63;
  if (wave >= NG) return;
  int beg = offs[wave], end = offs[wave + 1];
  float a0 = 0.f, a1 = 0.f, a2 = 0.f, a3 = 0.f;
  int n = beg;
  for (; n + 8 <= end; n += 8) {
    int i0 = sorted_sid[n + 0];
    int i1 = sorted_sid[n + 1];
    int i2 = sorted_sid[n + 2];
    int i3 = sorted_sid[n + 3];
    int i4 = sorted_sid[n + 4];
    int i5 = sorted_sid[n + 5];
    int i6 = sorted_sid[n + 6];
    int i7 = sorted_sid[n + 7];
    float v0 = snpT[(size_t)i0 * 64 + lane];
    float v1 = snpT[(size_t)i1 * 64 + lane];
    float v2 = snpT[(size_t)i2 * 64 + lane];
    float v3 = snpT[(size_t)i3 * 64 + lane];
    float v4 = snpT[(size_t)i4 * 64 + lane];
    float v5 = snpT[(size_t)i5 * 64 + lane];
    float v6 = snpT[(size_t)i6 * 64 + lane];
    float v7 = snpT[(size_t)i7 * 64 + lane];
    a0 += v0; a1 += v1; a2 += v2; a3 += v3;
    a0 += v4; a1 += v5; a2 += v6; a3 += v7;
  }
  for (; n + 4 <= end; n += 4) {
    int i0 = sorted_sid[n + 0];
    int i1 = sorted_sid[n + 1];
    int i2 = sorted_sid[n + 2];
    int i3 = sorted_sid[n + 3];
    a0 += snpT[(size_t)i0 * 64 + lane];
    a1 += snpT[(size_t)i1 * 64 + lane];
    a2 += snpT[(size_t)i2 * 64 + lane];
    a3 += snpT[(size_t)i3 * 64 + lane];
  }
  for (; n < end; n++) a0 += snpT[(size_t)sorted_sid[n] * 64 + lane];
  geneT[(size_t)wave * 64 + lane] = (a0 + a1) + (a2 + a3);
}

// ---------------- split-K GEMM, 128 cols/block, LDS-staged X, depth-2 W prefetch ----
// partial layout: [col][slice][b] so the reduce streams contiguously.
template <int KPSMAX>
__global__ __launch_bounds__(256) void k_gemm_stream2(const float* __restrict__ XT,
                                                      const float* __restrict__ Wm,
                                                      float* __restrict__ partial,
                                                      int KTOT, int kPerSlice,
                                                      int NCOLS) {
  __shared__ float xs[KPSMAX * 64];
  int tid = threadIdx.x;
  int lane = tid & 63;
  int wv = tid >> 6;
  int c0 = blockIdx.x * 128 + lane * 2;
  int b0 = wv * 16;
  int nslice = gridDim.y;
  int kBeg = blockIdx.y * kPerSlice;
  int kEnd = KTOT < kBeg + kPerSlice ? KTOT : kBeg + kPerSlice;
  int kc = kEnd - kBeg;

  // stage X slice into LDS (coalesced float4)
  {
    const float4* src = (const float4*)(XT + (size_t)kBeg * 64);
    float4* dst = (float4*)xs;
    for (int i = tid; i < kc * 16; i += 256) dst[i] = src[i];
  }
  __syncthreads();

  float acc0[16], acc1[16];
#pragma unroll
  for (int j = 0; j < 16; j++) { acc0[j] = 0.f; acc1[j] = 0.f; }

  const float* wp = Wm + (size_t)kBeg * NCOLS + c0;
  float2 w0 = make_float2(0.f, 0.f);
  float2 w1 = make_float2(0.f, 0.f);
  if (kc > 0) w0 = *(const float2*)(wp);
  if (kc > 1) w1 = *(const float2*)(wp + NCOLS);

  int kk = 0;
#pragma unroll 2
  for (; kk + 2 < kc; kk++) {
    float2 wn = *(const float2*)(wp + (size_t)(kk + 2) * NCOLS);  // prefetch depth 2
    const float4* xp = (const float4*)(xs + kk * 64 + b0);
    float4 g0 = xp[0], g1 = xp[1], g2 = xp[2], g3 = xp[3];
    float gg[16];
    gg[0] = g0.x; gg[1] = g0.y; gg[2] = g0.z; gg[3] = g0.w;
    gg[4] = g1.x; gg[5] = g1.y; gg[6] = g1.z; gg[7] = g1.w;
    gg[8] = g2.x; gg[9] = g2.y; gg[10] = g2.z; gg[11] = g2.w;
    gg[12] = g3.x; gg[13] = g3.y; gg[14] = g3.z; gg[15] = g3.w;
#pragma unroll
    for (int j = 0; j < 16; j++) {
      acc0[j] = fmaf(w0.x, gg[j], acc0[j]);
      acc1[j] = fmaf(w0.y, gg[j], acc1[j]);
    }
    w0 = w1; w1 = wn;
  }
  for (; kk < kc; kk++) {
    const float4* xp = (const float4*)(xs + kk * 64 + b0);
    float4 g0 = xp[0], g1 = xp[1], g2 = xp[2], g3 = xp[3];
    float gg[16];
    gg[0] = g0.x; gg[1] = g0.y; gg[2] = g0.z; gg[3] = g0.w;
    gg[4] = g1.x; gg[5] = g1.y; gg[6] = g1.z; gg[7] = g1.w;
    gg[8] = g2.x; gg[9] = g2.y; gg[10] = g2.z; gg[11] = g2.w;
    gg[12] = g3.x; gg[13] = g3.y; gg[14] = g3.z; gg[15] = g3.w;
#pragma unroll
    for (int j = 0; j < 16; j++) {
      acc0[j] = fmaf(w0.x, gg[j], acc0[j]);
      acc1[j] = fmaf(w0.y, gg[j], acc1[j]);
    }
    w0 = w1;
  }

#pragma unroll
  for (int i = 0; i < 2; i++) {
    const float* a = (i == 0) ? acc0 : acc1;
    float4* dst = (float4*)(partial + ((size_t)(c0 + i) * nslice + blockIdx.y) * 64 + b0);
#pragma unroll
    for (int q = 0; q < 4; q++) {
      float4 vv;
      vv.x = a[q * 4 + 0]; vv.y = a[q * 4 + 1];
      vv.z = a[q * 4 + 2]; vv.w = a[q * 4 + 3];
      dst[q] = vv;
    }
  }
}

// ---------------- fused split-K reduce + BatchNorm + ReLU ----------------
// partial layout: [col][slice][b] -> per-column data is contiguous (S*256 B)
__global__ __launch_bounds__(256) void k_reduce_bn(const float* __restrict__ partial,
                                                   int S,
                                                   const float* __restrict__ gamma,
                                                   const float* __restrict__ beta,
                                                   float* __restrict__ outT) {
  int n = blockIdx.x * 4 + (threadIdx.x >> 6);
  int b = threadIdx.x & 63;
  const float* p = partial + (size_t)n * S * 64 + b;
  float x0 = 0.f, x1 = 0.f, x2 = 0.f, x3 = 0.f;
  float x4 = 0.f, x5 = 0.f, x6 = 0.f, x7 = 0.f;
  int s = 0;
  for (; s + 8 <= S; s += 8) {
    x0 += p[(s + 0) * 64];
    x1 += p[(s + 1) * 64];
    x2 += p[(s + 2) * 64];
    x3 += p[(s + 3) * 64];
    x4 += p[(s + 4) * 64];
    x5 += p[(s + 5) * 64];
    x6 += p[(s + 6) * 64];
    x7 += p[(s + 7) * 64];
  }
  for (; s < S; s++) x0 += p[s * 64];
  float x = ((x0 + x1) + (x2 + x3)) + ((x4 + x5) + (x6 + x7));
  float s1 = x, s2 = x * x;
#pragma unroll
  for (int d = 32; d > 0; d >>= 1) {
    s1 += __shfl_xor(s1, d, 64);
    s2 += __shfl_xor(s2, d, 64);
  }
  float m = s1 * (1.f / 64.f);
  float v = s2 * (1.f / 64.f) - m * m;
  float y = gamma[n] * (x - m) * rsqrtf(v + EPS_) + beta[n];
  outT[(size_t)n * 64 + b] = fmaxf(y, 0.f);
}

// ---------------- head ----------------
__global__ __launch_bounds__(64) void k_head(const float* __restrict__ h2T,
                                             const float* __restrict__ W3,
                                             const float* __restrict__ b3,
                                             float* __restrict__ out) {
  int b = threadIdx.x;
  float acc = 0.f;
  for (int k = 0; k < 256; k++) acc = fmaf(h2T[(size_t)k * 64 + b], W3[k], acc);
  out[b] = acc + b3[0];
}

// ---------------- workspace layout (4 B elements) ----------------
static constexpr int S1 = 125;   // 125 * 160 = 20000 exactly; grid (8, 125) = 1000 blocks
static constexpr int S2 = 64;    // 64 * 16 = 1024 exactly; grid (2, 64)
static constexpr size_t N_W = NS;                        // 500,000
static constexpr size_t N_SNPT = (size_t)NS * 64;        // 32,000,000
static constexpr size_t N_GENET = (size_t)NG * 64;       // 1,280,000
static constexpr size_t N_P1 = (size_t)S1 * 1024 * 64;   // 8,192,000 (aliases snpT)
static constexpr size_t N_P2 = (size_t)S2 * 256 * 64;    // 1,048,576 (aliases snpT)

extern "C" void kernel_launch(void* const* d_in, const int* in_sizes, int n_in,
                              void* d_out, int out_size, void* d_ws, size_t ws_size,
                              hipStream_t stream) {
  const float* snp       = (const float*)d_in[0];
  const int*   snp_ids   = (const int*)d_in[1];
  const int*   node_gene = (const int*)d_in[2];
  const float* filters   = (const float*)d_in[3];
  const float* W1        = (const float*)d_in[4];
  const float* g1        = (const float*)d_in[6];
  const float* beta1     = (const float*)d_in[7];
  const float* W2        = (const float*)d_in[8];
  const float* g2        = (const float*)d_in[10];
  const float* beta2     = (const float*)d_in[11];
  const float* W3        = (const float*)d_in[12];
  const float* b3        = (const float*)d_in[13];
  float* out = (float*)d_out;
  float* ws  = (float*)d_ws;

  float* w      = ws;                 // 500,000
  float* snpT   = ws + N_W;           // 32,000,000 (dead after accum)
  float* p1     = snpT;               // alias
  float* p2     = p1 + N_P1;          // alias (8.2M + 1.0M < 32M ok)
  float* geneT  = snpT + N_SNPT;      // 1,280,000
  float* h1T    = geneT + N_GENET;    // 65,536
  float* h2T    = h1T + 65536;        // 16,384
  int* cnt      = (int*)(h2T + 16384);
  int* offs     = cnt + NG;           // NG+1 used, pad to 20064
  int* cursor   = offs + 20064;
  int* sorted   = cursor + NG;        // 600,000
  unsigned char* used = (unsigned char*)(sorted + NN);  // 500,000 bytes (+pad)

  // zero histogram counters + used map
  hipMemsetAsync(cnt, 0, NG * sizeof(int), stream);
  hipMemsetAsync(used, 0, NS, stream);

  // w = mean_f filters; copy filters -> out[64..]
  k_w_copy<<<(NS / 4 + 255) / 256, 256, 0, stream>>>(filters, w, out + 64);

  // counting sort of nodes by gene + used-sid mark (merged first pass)
  k_hist_mark<<<(NN + 255) / 256, 256, 0, stream>>>(snp_ids, node_gene, cnt, used);
  k_scan<<<1, 1024, 0, stream>>>(cnt, offs, cursor);
  k_sortnodes<<<(NN + 255) / 256, 256, 0, stream>>>(snp_ids, node_gene, cursor, sorted);

  // transpose v5 (pipelined, 4 tiles/block) + gene accumulation
  {
    int nt = (NS + 63) / 64;        // 7813
    int nb = (nt + 3) / 4;          // 1954
    k_transpose<<<nb, 256, 0, stream>>>(snp, w, used, snpT);
  }
  k_accum_T<<<(NG * 64) / 256, 256, 0, stream>>>(snpT, offs, sorted, geneT);

  // MLP layer 1: [64,20000] x [20000,1024]  -- 8 col-blocks x 125 slices
  k_gemm_stream2<160><<<dim3(8, S1), 256, 0, stream>>>(geneT, W1, p1, NG, 160, 1024);
  k_reduce_bn<<<1024 / 4, 256, 0, stream>>>(p1, S1, g1, beta1, h1T);

  // MLP layer 2: [64,1024] x [1024,256]  -- 2 col-blocks x 64 slices
  k_gemm_stream2<16><<<dim3(2, S2), 256, 0, stream>>>(h1T, W2, p2, 1024, 16, 256);
  k_reduce_bn<<<256 / 4, 256, 0, stream>>>(p2, S2, g2, beta2, h2T);

  // head
  k_head<<<1, 64, 0, stream>>>(h2T, W3, b3, out);
}

// Round 7
// 483.510 us; speedup vs baseline: 1.0105x; 1.0105x over previous
//
#include <hip/hip_runtime.h>

#define NS 500000
#define NG 20000
#define NN 600000
#define NF 8
#define EPS_ 1e-5f

// ---------------- K1: w = mean_f filters; also copy filters -> out ----------------
__global__ __launch_bounds__(256) void k_w_copy(const float* __restrict__ filters,
                                                float* __restrict__ w,
                                                float* __restrict__ out_f) {
  int i = blockIdx.x * 256 + threadIdx.x;
  const int n4 = NS / 4;  // 125000
  if (i >= n4) return;
  const float4* f4 = (const float4*)filters;
  float4* o4 = (float4*)out_f;
  float sx = 0.f, sy = 0.f, sz = 0.f, sw = 0.f;
#pragma unroll
  for (int f = 0; f < NF; f++) {
    float4 v = f4[(size_t)f * n4 + i];
    o4[(size_t)f * n4 + i] = v;
    sx += v.x; sy += v.y; sz += v.z; sw += v.w;
  }
  float4 r;
  r.x = sx * 0.125f; r.y = sy * 0.125f; r.z = sz * 0.125f; r.w = sw * 0.125f;
  ((float4*)w)[i] = r;
}

// ---------------- hist + mark used sids (merged, one pass) ----------------
__global__ __launch_bounds__(256) void k_hist_mark(const int* __restrict__ snp_ids,
                                                   const int* __restrict__ node_gene,
                                                   int* __restrict__ cnt,
                                                   unsigned char* __restrict__ used) {
  int j = blockIdx.x * 256 + threadIdx.x;
  if (j < NN) {
    used[snp_ids[j]] = 1;
    atomicAdd(&cnt[node_gene[j]], 1);
  }
}

__global__ __launch_bounds__(1024) void k_scan(const int* __restrict__ cnt,
                                               int* __restrict__ offs,
                                               int* __restrict__ cursor) {
  __shared__ int part[1024];
  int t = threadIdx.x;
  int base = t * 20;  // 1024*20 = 20480 >= 20000
  int s = 0;
  for (int i = 0; i < 20; i++) {
    int g = base + i;
    if (g < NG) s += cnt[g];
  }
  part[t] = s;
  __syncthreads();
  for (int d = 1; d < 1024; d <<= 1) {
    int v = 0;
    if (t >= d) v = part[t - d];
    __syncthreads();
    part[t] += v;
    __syncthreads();
  }
  int run = part[t] - s;
  for (int i = 0; i < 20; i++) {
    int g = base + i;
    if (g < NG) {
      offs[g] = run;
      cursor[g] = run;
      run += cnt[g];
    }
  }
  if (t == 1023) offs[NG] = part[1023];
}

__global__ __launch_bounds__(256) void k_sortnodes(const int* __restrict__ snp_ids,
                                                   const int* __restrict__ node_gene,
                                                   int* __restrict__ cursor,
                                                   int* __restrict__ sorted_sid) {
  int j = blockIdx.x * 256 + threadIdx.x;
  if (j >= NN) return;
  int g = node_gene[j];
  int pos = atomicAdd(&cursor[g], 1);
  sorted_sid[pos] = snp_ids[j];
}

// ---------------- transpose v6: 128-sid x 64-batch tiles, flat schedule ----------
// H1 test: 512B contiguous read segments per row (was 256B), halving row visits.
// LDS float4-chunk layout: chunk(b,f) at [b*32 + (f ^ (b&31))], f = sid/4 within tile.
// Write phase conflict-free (consecutive chunks per lane); read phase 2-way (free).
__global__ __launch_bounds__(256) void k_transpose(const float* __restrict__ snp,
                                                   const float* __restrict__ w,
                                                   const unsigned char* __restrict__ used,
                                                   float* __restrict__ snpT) {
  __shared__ float tile[128 * 64];  // 32 KB
  int t = threadIdx.x;
  int s0 = blockIdx.x * 128;

  // ---- load phase: f = float4 col (0..31), rows b = i*8 + rb, 8 loads/thread ----
  int f = t & 31;
  int rb = t >> 5;  // 0..7
  bool okf = (s0 + 4 * f + 4 <= NS);
  float4 w4 = make_float4(0.f, 0.f, 0.f, 0.f);
  if (okf) w4 = *(const float4*)(w + s0 + 4 * f);
  float4 v[8];
#pragma unroll
  for (int i = 0; i < 8; i++) {
    int b = i * 8 + rb;
    v[i] = make_float4(0.f, 0.f, 0.f, 0.f);
    if (okf) v[i] = *(const float4*)(snp + (size_t)b * NS + s0 + 4 * f);
  }
#pragma unroll
  for (int i = 0; i < 8; i++) {
    int b = i * 8 + rb;
    float4 x = v[i];
    x.x *= w4.x; x.y *= w4.y; x.z *= w4.z; x.w *= w4.w;
    ((float4*)tile)[b * 32 + (f ^ (b & 31))] = x;
  }
  __syncthreads();

  // ---- store phase: lane = batch b, wave sq covers 32 sids (8 chunks) ----
  int b = t & 63;
  int sq = t >> 6;
  int ubase = s0 + sq * 32;
  unsigned u32s[8];
  if (ubase + 32 <= NS) {
    uint4 ua = *(const uint4*)(used + ubase);        // broadcast (uniform addr)
    uint4 ub = *(const uint4*)(used + ubase + 16);
    u32s[0] = ua.x; u32s[1] = ua.y; u32s[2] = ua.z; u32s[3] = ua.w;
    u32s[4] = ub.x; u32s[5] = ub.y; u32s[6] = ub.z; u32s[7] = ub.w;
  } else {
#pragma unroll
    for (int i = 0; i < 8; i++) {
      unsigned vv = 0;
#pragma unroll
      for (int k = 0; k < 4; k++) {
        int s = ubase + 4 * i + k;
        if (s < NS && used[s]) vv |= (1u << (8 * k));
      }
      u32s[i] = vv;
    }
  }
#pragma unroll
  for (int i = 0; i < 8; i++) {
    int s4 = sq * 8 + i;
    float4 x = ((const float4*)tile)[b * 32 + (s4 ^ (b & 31))];
    int sb = s0 + 4 * s4;
    float xv[4] = {x.x, x.y, x.z, x.w};
#pragma unroll
    for (int k = 0; k < 4; k++) {
      int s = sb + k;
      bool u = ((u32s[i] >> (8 * k)) & 0xFFu) != 0;  // wave-uniform
      if (s < NS && u) snpT[(size_t)s * 64 + b] = xv[k];
    }
  }
}

// ---------------- accum v3: wave per gene, lane = batch, 8-node ILP ----------------
__global__ __launch_bounds__(256) void k_accum_T(const float* __restrict__ snpT,
                                                 const int* __restrict__ offs,
                                                 const int* __restrict__ sorted_sid,
                                                 float* __restrict__ geneT) {
  int wave = (blockIdx.x * 256 + threadIdx.x) >> 6;
  int lane = threadIdx.x & 63;
  if (wave >= NG) return;
  int beg = offs[wave], end = offs[wave + 1];
  float a0 = 0.f, a1 = 0.f, a2 = 0.f, a3 = 0.f;
  int n = beg;
  for (; n + 8 <= end; n += 8) {
    int i0 = sorted_sid[n + 0];
    int i1 = sorted_sid[n + 1];
    int i2 = sorted_sid[n + 2];
    int i3 = sorted_sid[n + 3];
    int i4 = sorted_sid[n + 4];
    int i5 = sorted_sid[n + 5];
    int i6 = sorted_sid[n + 6];
    int i7 = sorted_sid[n + 7];
    float v0 = snpT[(size_t)i0 * 64 + lane];
    float v1 = snpT[(size_t)i1 * 64 + lane];
    float v2 = snpT[(size_t)i2 * 64 + lane];
    float v3 = snpT[(size_t)i3 * 64 + lane];
    float v4 = snpT[(size_t)i4 * 64 + lane];
    float v5 = snpT[(size_t)i5 * 64 + lane];
    float v6 = snpT[(size_t)i6 * 64 + lane];
    float v7 = snpT[(size_t)i7 * 64 + lane];
    a0 += v0; a1 += v1; a2 += v2; a3 += v3;
    a0 += v4; a1 += v5; a2 += v6; a3 += v7;
  }
  for (; n + 4 <= end; n += 4) {
    int i0 = sorted_sid[n + 0];
    int i1 = sorted_sid[n + 1];
    int i2 = sorted_sid[n + 2];
    int i3 = sorted_sid[n + 3];
    a0 += snpT[(size_t)i0 * 64 + lane];
    a1 += snpT[(size_t)i1 * 64 + lane];
    a2 += snpT[(size_t)i2 * 64 + lane];
    a3 += snpT[(size_t)i3 * 64 + lane];
  }
  for (; n < end; n++) a0 += snpT[(size_t)sorted_sid[n] * 64 + lane];
  geneT[(size_t)wave * 64 + lane] = (a0 + a1) + (a2 + a3);
}

// ---------------- split-K GEMM, 128 cols/block, LDS-staged X, depth-2 W prefetch ----
// partial layout: [col][slice][b] so the reduce streams contiguously.
template <int KPSMAX>
__global__ __launch_bounds__(256) void k_gemm_stream2(const float* __restrict__ XT,
                                                      const float* __restrict__ Wm,
                                                      float* __restrict__ partial,
                                                      int KTOT, int kPerSlice,
                                                      int NCOLS) {
  __shared__ float xs[KPSMAX * 64];
  int tid = threadIdx.x;
  int lane = tid & 63;
  int wv = tid >> 6;
  int c0 = blockIdx.x * 128 + lane * 2;
  int b0 = wv * 16;
  int nslice = gridDim.y;
  int kBeg = blockIdx.y * kPerSlice;
  int kEnd = KTOT < kBeg + kPerSlice ? KTOT : kBeg + kPerSlice;
  int kc = kEnd - kBeg;

  // stage X slice into LDS (coalesced float4)
  {
    const float4* src = (const float4*)(XT + (size_t)kBeg * 64);
    float4* dst = (float4*)xs;
    for (int i = tid; i < kc * 16; i += 256) dst[i] = src[i];
  }
  __syncthreads();

  float acc0[16], acc1[16];
#pragma unroll
  for (int j = 0; j < 16; j++) { acc0[j] = 0.f; acc1[j] = 0.f; }

  const float* wp = Wm + (size_t)kBeg * NCOLS + c0;
  float2 w0 = make_float2(0.f, 0.f);
  float2 w1 = make_float2(0.f, 0.f);
  if (kc > 0) w0 = *(const float2*)(wp);
  if (kc > 1) w1 = *(const float2*)(wp + NCOLS);

  int kk = 0;
#pragma unroll 2
  for (; kk + 2 < kc; kk++) {
    float2 wn = *(const float2*)(wp + (size_t)(kk + 2) * NCOLS);  // prefetch depth 2
    const float4* xp = (const float4*)(xs + kk * 64 + b0);
    float4 g0 = xp[0], g1 = xp[1], g2 = xp[2], g3 = xp[3];
    float gg[16];
    gg[0] = g0.x; gg[1] = g0.y; gg[2] = g0.z; gg[3] = g0.w;
    gg[4] = g1.x; gg[5] = g1.y; gg[6] = g1.z; gg[7] = g1.w;
    gg[8] = g2.x; gg[9] = g2.y; gg[10] = g2.z; gg[11] = g2.w;
    gg[12] = g3.x; gg[13] = g3.y; gg[14] = g3.z; gg[15] = g3.w;
#pragma unroll
    for (int j = 0; j < 16; j++) {
      acc0[j] = fmaf(w0.x, gg[j], acc0[j]);
      acc1[j] = fmaf(w0.y, gg[j], acc1[j]);
    }
    w0 = w1; w1 = wn;
  }
  for (; kk < kc; kk++) {
    const float4* xp = (const float4*)(xs + kk * 64 + b0);
    float4 g0 = xp[0], g1 = xp[1], g2 = xp[2], g3 = xp[3];
    float gg[16];
    gg[0] = g0.x; gg[1] = g0.y; gg[2] = g0.z; gg[3] = g0.w;
    gg[4] = g1.x; gg[5] = g1.y; gg[6] = g1.z; gg[7] = g1.w;
    gg[8] = g2.x; gg[9] = g2.y; gg[10] = g2.z; gg[11] = g2.w;
    gg[12] = g3.x; gg[13] = g3.y; gg[14] = g3.z; gg[15] = g3.w;
#pragma unroll
    for (int j = 0; j < 16; j++) {
      acc0[j] = fmaf(w0.x, gg[j], acc0[j]);
      acc1[j] = fmaf(w0.y, gg[j], acc1[j]);
    }
    w0 = w1;
  }

#pragma unroll
  for (int i = 0; i < 2; i++) {
    const float* a = (i == 0) ? acc0 : acc1;
    float4* dst = (float4*)(partial + ((size_t)(c0 + i) * nslice + blockIdx.y) * 64 + b0);
#pragma unroll
    for (int q = 0; q < 4; q++) {
      float4 vv;
      vv.x = a[q * 4 + 0]; vv.y = a[q * 4 + 1];
      vv.z = a[q * 4 + 2]; vv.w = a[q * 4 + 3];
      dst[q] = vv;
    }
  }
}

// ---------------- fused split-K reduce + BatchNorm + ReLU ----------------
// partial layout: [col][slice][b] -> per-column data is contiguous (S*256 B)
__global__ __launch_bounds__(256) void k_reduce_bn(const float* __restrict__ partial,
                                                   int S,
                                                   const float* __restrict__ gamma,
                                                   const float* __restrict__ beta,
                                                   float* __restrict__ outT) {
  int n = blockIdx.x * 4 + (threadIdx.x >> 6);
  int b = threadIdx.x & 63;
  const float* p = partial + (size_t)n * S * 64 + b;
  float x0 = 0.f, x1 = 0.f, x2 = 0.f, x3 = 0.f;
  float x4 = 0.f, x5 = 0.f, x6 = 0.f, x7 = 0.f;
  int s = 0;
  for (; s + 8 <= S; s += 8) {
    x0 += p[(s + 0) * 64];
    x1 += p[(s + 1) * 64];
    x2 += p[(s + 2) * 64];
    x3 += p[(s + 3) * 64];
    x4 += p[(s + 4) * 64];
    x5 += p[(s + 5) * 64];
    x6 += p[(s + 6) * 64];
    x7 += p[(s + 7) * 64];
  }
  for (; s < S; s++) x0 += p[s * 64];
  float x = ((x0 + x1) + (x2 + x3)) + ((x4 + x5) + (x6 + x7));
  float s1 = x, s2 = x * x;
#pragma unroll
  for (int d = 32; d > 0; d >>= 1) {
    s1 += __shfl_xor(s1, d, 64);
    s2 += __shfl_xor(s2, d, 64);
  }
  float m = s1 * (1.f / 64.f);
  float v = s2 * (1.f / 64.f) - m * m;
  float y = gamma[n] * (x - m) * rsqrtf(v + EPS_) + beta[n];
  outT[(size_t)n * 64 + b] = fmaxf(y, 0.f);
}

// ---------------- head ----------------
__global__ __launch_bounds__(64) void k_head(const float* __restrict__ h2T,
                                             const float* __restrict__ W3,
                                             const float* __restrict__ b3,
                                             float* __restrict__ out) {
  int b = threadIdx.x;
  float acc = 0.f;
  for (int k = 0; k < 256; k++) acc = fmaf(h2T[(size_t)k * 64 + b], W3[k], acc);
  out[b] = acc + b3[0];
}

// ---------------- workspace layout (4 B elements) ----------------
static constexpr int S1 = 125;   // 125 * 160 = 20000 exactly; grid (8, 125) = 1000 blocks
static constexpr int S2 = 64;    // 64 * 16 = 1024 exactly; grid (2, 64)
static constexpr size_t N_W = NS;                        // 500,000
static constexpr size_t N_SNPT = (size_t)NS * 64;        // 32,000,000
static constexpr size_t N_GENET = (size_t)NG * 64;       // 1,280,000
static constexpr size_t N_P1 = (size_t)S1 * 1024 * 64;   // 8,192,000 (aliases snpT)
static constexpr size_t N_P2 = (size_t)S2 * 256 * 64;    // 1,048,576 (aliases snpT)

extern "C" void kernel_launch(void* const* d_in, const int* in_sizes, int n_in,
                              void* d_out, int out_size, void* d_ws, size_t ws_size,
                              hipStream_t stream) {
  const float* snp       = (const float*)d_in[0];
  const int*   snp_ids   = (const int*)d_in[1];
  const int*   node_gene = (const int*)d_in[2];
  const float* filters   = (const float*)d_in[3];
  const float* W1        = (const float*)d_in[4];
  const float* g1        = (const float*)d_in[6];
  const float* beta1     = (const float*)d_in[7];
  const float* W2        = (const float*)d_in[8];
  const float* g2        = (const float*)d_in[10];
  const float* beta2     = (const float*)d_in[11];
  const float* W3        = (const float*)d_in[12];
  const float* b3        = (const float*)d_in[13];
  float* out = (float*)d_out;
  float* ws  = (float*)d_ws;

  float* w      = ws;                 // 500,000
  float* snpT   = ws + N_W;           // 32,000,000 (dead after accum)
  float* p1     = snpT;               // alias
  float* p2     = p1 + N_P1;          // alias (8.2M + 1.0M < 32M ok)
  float* geneT  = snpT + N_SNPT;      // 1,280,000
  float* h1T    = geneT + N_GENET;    // 65,536
  float* h2T    = h1T + 65536;        // 16,384
  int* cnt      = (int*)(h2T + 16384);
  int* offs     = cnt + NG;           // NG+1 used, pad to 20064
  int* cursor   = offs + 20064;
  int* sorted   = cursor + NG;        // 600,000
  unsigned char* used = (unsigned char*)(sorted + NN);  // 500,000 bytes (+pad)

  // zero histogram counters + used map
  hipMemsetAsync(cnt, 0, NG * sizeof(int), stream);
  hipMemsetAsync(used, 0, NS, stream);

  // w = mean_f filters; copy filters -> out[64..]
  k_w_copy<<<(NS / 4 + 255) / 256, 256, 0, stream>>>(filters, w, out + 64);

  // counting sort of nodes by gene + used-sid mark (merged first pass)
  k_hist_mark<<<(NN + 255) / 256, 256, 0, stream>>>(snp_ids, node_gene, cnt, used);
  k_scan<<<1, 1024, 0, stream>>>(cnt, offs, cursor);
  k_sortnodes<<<(NN + 255) / 256, 256, 0, stream>>>(snp_ids, node_gene, cursor, sorted);

  // transpose v6 (128-sid tiles) + gene accumulation
  k_transpose<<<(NS + 127) / 128, 256, 0, stream>>>(snp, w, used, snpT);
  k_accum_T<<<(NG * 64) / 256, 256, 0, stream>>>(snpT, offs, sorted, geneT);

  // MLP layer 1: [64,20000] x [20000,1024]  -- 8 col-blocks x 125 slices
  k_gemm_stream2<160><<<dim3(8, S1), 256, 0, stream>>>(geneT, W1, p1, NG, 160, 1024);
  k_reduce_bn<<<1024 / 4, 256, 0, stream>>>(p1, S1, g1, beta1, h1T);

  // MLP layer 2: [64,1024] x [1024,256]  -- 2 col-blocks x 64 slices
  k_gemm_stream2<16><<<dim3(2, S2), 256, 0, stream>>>(h1T, W2, p2, 1024, 16, 256);
  k_reduce_bn<<<256 / 4, 256, 0, stream>>>(p2, S2, g2, beta2, h2T);

  // head
  k_head<<<1, 64, 0, stream>>>(h2T, W3, b3, out);
}